// Round 9
// baseline (816.593 us; speedup 1.0000x reference)
//
#include <hip/hip_runtime.h>
#include <math.h>

#define B   16
#define NW  30
#define NE  19
#define NF  128
#define NH  8
#define NC  80
#define ND  640
#define NN  570   /* NW*NE */
#define NROW (B*NN)   /* 9120 = 285*32 */
#define NBLK 1024     /* mega grid: 4 blocks/CU x 256 CUs, all resident */

typedef _Float16 f16x2 __attribute__((ext_vector_type(2)));
typedef _Float16 f16x4 __attribute__((ext_vector_type(4)));
typedef _Float16 f16x8 __attribute__((ext_vector_type(8)));
typedef float    f32x16 __attribute__((ext_vector_type(16)));

// workspace layout (float offsets)
#define WT_OFF   0
#define WT_SZ    (1280*128)               /* wph+wpl */
#define XL_OFF   (WT_OFF + WT_SZ)
#define XLR16_SZ (B*NN*ND/2)              /* f16 xl/xr */
#define XR_OFF   (XL_OFF + XLR16_SZ)
#define XT_OFF   (XR_OFF + XLR16_SZ)      /* xph+xpl */
#define SCP_OFF  (XT_OFF + 2*(NROW*NF/2))
#define SCP_SZ   (NH*B*NN)
#define QP_OFF   (SCP_OFF + SCP_SZ)
#define CTR_OFF  (QP_OFF + SCP_SZ)        /* 64 uints: bar[3] + gen */

__device__ __forceinline__ float dot8(f16x8 zm, f16x8 a8, float acc){
#if __has_builtin(__builtin_amdgcn_fdot2)
  acc = __builtin_amdgcn_fdot2(__builtin_shufflevector(zm, zm, 0, 1),
                               __builtin_shufflevector(a8, a8, 0, 1), acc, false);
  acc = __builtin_amdgcn_fdot2(__builtin_shufflevector(zm, zm, 2, 3),
                               __builtin_shufflevector(a8, a8, 2, 3), acc, false);
  acc = __builtin_amdgcn_fdot2(__builtin_shufflevector(zm, zm, 4, 5),
                               __builtin_shufflevector(a8, a8, 4, 5), acc, false);
  acc = __builtin_amdgcn_fdot2(__builtin_shufflevector(zm, zm, 6, 7),
                               __builtin_shufflevector(a8, a8, 6, 7), acc, false);
#else
  #pragma unroll
  for (int j = 0; j < 8; ++j) acc = fmaf((float)zm[j], (float)a8[j], acc);
#endif
  return acc;
}

// generation grid-barrier. All NBLK blocks resident by construction
// (launch_bounds(256,4) => 4 blocks/CU, grid = 4*256). Per-phase arrival
// counter (no reuse hazard); gen released by last arriver. threadfence by
// ALL threads before arrival publishes this block's global writes
// device-wide (cross-XCD); acquire load + fence before proceeding.
__device__ __forceinline__ void grid_barrier(unsigned* bar, unsigned* gen,
                                             unsigned phase){
  __threadfence();
  __syncthreads();
  if (threadIdx.x == 0){
    unsigned a = atomicAdd(bar, 1u) + 1u;
    if (a == NBLK) atomicAdd(gen, 1u);
    while (__hip_atomic_load(gen, __ATOMIC_ACQUIRE,
                             __HIP_MEMORY_SCOPE_AGENT) < phase){
#if __has_builtin(__builtin_amdgcn_s_sleep)
      __builtin_amdgcn_s_sleep(2);
#endif
    }
    __threadfence();
  }
  __syncthreads();
}

__global__ __launch_bounds__(64) void kinit(unsigned* __restrict__ ctr){
  if (threadIdx.x < 8) ctr[threadIdx.x] = 0u;
}

// ---------------------------------------------------------------------------
// MEGA: all four stages in one dispatch, separated by grid barriers.
// R22: removes 3 launch/drain gaps AND finally makes the pipeline duration
// directly visible in the top-5 table (fills hid every kernel so far).
__global__ __launch_bounds__(256, 4) void mega(
    const float* __restrict__ Wl, const float* __restrict__ Wr,
    const float* __restrict__ x,
    const float* __restrict__ bl, const float* __restrict__ br,
    const float* __restrict__ att, const float* __restrict__ cb,
    const float* __restrict__ wpool, const float* __restrict__ bpool,
    const float* __restrict__ wfc, const float* __restrict__ bfc,
    _Float16* __restrict__ wph, _Float16* __restrict__ wpl,
    _Float16* __restrict__ xph, _Float16* __restrict__ xpl,
    _Float16* __restrict__ xl, _Float16* __restrict__ xr,
    float* __restrict__ scp, float* __restrict__ qp,
    float* __restrict__ out, unsigned* __restrict__ ctr)
{
  int bid = blockIdx.x, t = threadIdx.x;
  __shared__ __attribute__((aligned(16))) char smem[16640];

  // ===== phase A: operand prep (k0) =====
  if (bid < 480){
    float* ns = (float*)smem;            /* 19*132 floats = 10,032 B */
    int w = bid % NW, b = bid / NW;
    const float4* xs = (const float4*)(x + (size_t)((b*NW + w)*NF)*NE);
    for (int i = t; i < 608; i += 256){
      float4 v = xs[i];
      int idx = 4*i;
      float vv[4] = {v.x, v.y, v.z, v.w};
      #pragma unroll
      for (int k = 0; k < 4; ++k){
        int f = (idx + k) / NE, el = (idx + k) % NE;
        ns[el*132 + f] = vv[k];
      }
    }
    __syncthreads();
    for (int i = t; i < 608; i += 256){
      int el = i >> 5, k = (i & 31) * 4;
      float4 v = *(const float4*)&ns[el*132 + k];
      _Float16 h0=(_Float16)v.x, h1=(_Float16)v.y, h2=(_Float16)v.z, h3=(_Float16)v.w;
      f16x4 hv = {h0, h1, h2, h3};
      f16x4 lv = {(_Float16)(v.x-(float)h0), (_Float16)(v.y-(float)h1),
                  (_Float16)(v.z-(float)h2), (_Float16)(v.w-(float)h3)};
      int n = (b*NW + w)*NE + el;
      int s = k >> 4, hh = (k >> 3) & 1, off = k & 7;
      size_t chunk = (((size_t)(n >> 5)*8 + s)*64 + hh*32 + (n & 31))*8 + off;
      *(f16x4*)(xph + chunk) = hv;
      *(f16x4*)(xpl + chunk) = lv;
    }
  } else {
    int i = (bid - 480)*256 + t;
    if (i < 40960){
      int dd = i >> 5, k = (i & 31) * 4;
      const float* srcp = (dd < 640) ? (Wl + dd*NF + k) : (Wr + (dd-640)*NF + k);
      float4 v = *(const float4*)srcp;
      _Float16 h0=(_Float16)v.x, h1=(_Float16)v.y, h2=(_Float16)v.z, h3=(_Float16)v.w;
      f16x4 hv = {h0, h1, h2, h3};
      f16x4 lv = {(_Float16)(v.x-(float)h0), (_Float16)(v.y-(float)h1),
                  (_Float16)(v.z-(float)h2), (_Float16)(v.w-(float)h3)};
      int s = k >> 4, hh = (k >> 3) & 1, off = k & 7;
      size_t chunk = (((size_t)(dd >> 5)*8 + s)*64 + hh*32 + (dd & 31))*8 + off;
      *(f16x4*)(wph + chunk) = hv;
      *(f16x4*)(wpl + chunk) = lv;
    }
  }
  grid_barrier(ctr + 0, ctr + 3, 1);

  // ===== phase B: GEMM (k1), grid-strided 2850 jobs =====
  {
    _Float16* ash = (_Float16*)smem;           /* 8,192 B */
    _Float16* asl = (_Float16*)(smem + 8192);  /* 8,192 B */
    int wave = t >> 6, lane = t & 63;
    for (int j = bid; j < 2850; j += NBLK){
      int mt = j % 285, y = j / 285;
      __syncthreads();                         /* protect prior iter LDS */
      const f16x8* gh = (const f16x8*)(xph + (size_t)mt*4096);
      const f16x8* gl = (const f16x8*)(xpl + (size_t)mt*4096);
      ((f16x8*)ash)[t]     = gh[t];
      ((f16x8*)ash)[t+256] = gh[t+256];
      ((f16x8*)asl)[t]     = gl[t];
      ((f16x8*)asl)[t+256] = gl[t+256];
      __syncthreads();

      int nt = y*4 + wave;
      const f16x8* sah = (const f16x8*)ash + lane;
      const f16x8* sal = (const f16x8*)asl + lane;
      const f16x8* pbh = (const f16x8*)wph + (size_t)nt*512 + lane;
      const f16x8* pbl = (const f16x8*)wpl + (size_t)nt*512 + lane;

      f32x16 acc = {};
      #pragma unroll
      for (int s = 0; s < 8; ++s){
        f16x8 a_h = sah[s*64];
        f16x8 b_h = pbh[s*64];
        f16x8 a_l = sal[s*64];
        f16x8 b_l = pbl[s*64];
        /* swapped operands (R20-validated): same products, same order */
        acc = __builtin_amdgcn_mfma_f32_32x32x16_f16(b_h, a_h, acc, 0, 0, 0);
        acc = __builtin_amdgcn_mfma_f32_32x32x16_f16(b_h, a_l, acc, 0, 0, 0);
        acc = __builtin_amdgcn_mfma_f32_32x32x16_f16(b_l, a_h, acc, 0, 0, 0);
      }
      int node = mt*32 + (lane & 31);
      int cl4  = 4*(lane >> 5);
      #pragma unroll
      for (int g = 0; g < 4; ++g){
        int cn = nt*32 + cl4 + 8*g;
        bool isl = cn < 640;
        int col = isl ? cn : cn - 640;
        const float* bp = isl ? bl : br;
        _Float16* dst   = isl ? xl : xr;
        float4 bb = *(const float4*)(bp + col);
        f16x4 o = {(_Float16)(acc[4*g+0] + bb.x), (_Float16)(acc[4*g+1] + bb.y),
                   (_Float16)(acc[4*g+2] + bb.z), (_Float16)(acc[4*g+3] + bb.w)};
        *(f16x4*)(dst + (size_t)node*ND + col) = o;
      }
    }
  }
  grid_barrier(ctr + 1, ctr + 3, 2);

  // ===== phase C: GAT (k2), grid-strided 3840 jobs, R14 body =====
  {
    _Float16* xl_s   = (_Float16*)smem;              /* 57*88 = 10,032 B */
    _Float16* xr_s   = (_Float16*)(smem + 10032);    /* 19*88 = 3,344 B */
    _Float16* atth_s = (_Float16*)(smem + 13376);    /* 160 B */
    float* cb_s   = (float*)(smem + 13536);
    float* wp_s   = (float*)(smem + 13856);
    float* wf_s   = (float*)(smem + 14176);
    float* e_s    = (float*)(smem + 14496);          /* 19*22 = 1,672 B */
    float* score_s= (float*)(smem + 16168);
    float* q_s    = (float*)(smem + 16244);

    for (int j = bid; j < 3840; j += NBLK){
      int w = j % NW, r = j / NW, b = r % B, h = r / B;
      __syncthreads();                               /* protect prior iter */
      if (t < 19){ score_s[t] = 0.f; q_s[t] = 0.f; }
      const bool vp = (w > 0), vn = (w < NW-1);

      for (int i = t; i < 570; i += 256){
        int row = i / 10, c8 = i % 10;
        int node = -1;
        if (row < 19)        node = w*NE + row;
        else if (row < 38) { if (vp) node = (w-1)*NE + (row-19); }
        else               { if (vn) node = (w+1)*NE + (row-38); }
        if (node >= 0)
          *(f16x8*)&xl_s[row*88 + 8*c8] =
            *(const f16x8*)(xl + (size_t)(b*NN + node)*ND + h*80 + 8*c8);
      }
      for (int i = t; i < 190; i += 256){
        int row = i / 10, c8 = i % 10;
        int node = w*NE + row;
        *(f16x8*)&xr_s[row*88 + 8*c8] =
          *(const f16x8*)(xr + (size_t)(b*NN + node)*ND + h*80 + 8*c8);
      }
      if (t < 80){
        int a = t / 20, c4 = t % 20;
        if (a == 0){
          float4 v = *(const float4*)(att + h*80 + 4*c4);
          f16x4 hv = {(_Float16)v.x, (_Float16)v.y, (_Float16)v.z, (_Float16)v.w};
          *(f16x4*)&atth_s[4*c4] = hv;
        } else {
          const float* sp0 = (a == 1) ? cb + h*80 : (a == 2) ? wpool + h*80 : wfc + h*80;
          float*       dp  = (a == 1) ? cb_s      : (a == 2) ? wp_s        : wf_s;
          *(float4*)&dp[4*c4] = *(const float4*)(sp0 + 4*c4);
        }
      }
      __syncthreads();

      // e[dst][s] = sum_c lrelu(xl[src]+xr[dst]) * att
      for (int eid = t; eid < 399; eid += 256){
        int s = eid / 19, dst = eid % 19;
        if ((s == 19 && !vp) || (s == 20 && !vn)) continue;
        int row = (s < 19) ? s : (s == 19 ? 19 + dst : 38 + dst);
        const f16x8* xlp = (const f16x8*)&xl_s[row*88];
        const f16x8* xrp = (const f16x8*)&xr_s[dst*88];
        const f16x8* ap  = (const f16x8*)atth_s;
        float acc = 0.f;
        #pragma unroll 2
        for (int c8 = 0; c8 < 10; ++c8){
          f16x8 z  = xlp[c8] + xrp[c8];
          f16x8 zm = __builtin_elementwise_max(z, z * (_Float16)0.2f);
          acc = dot8(zm, ap[c8], acc);
        }
        e_s[dst*22 + s] = acc;
      }
      __syncthreads();

      // R22: wave-parallel softmax — 8 lanes per dst (depth-3 shfl tree)
      // replaces the 21-iteration serial LDS+exp chain (19/256 threads).
      if (t < 152){
        int dst = t >> 3, lj = t & 7;
        float m = -1e30f;
        #pragma unroll
        for (int q = 0; q < 3; ++q){
          int s = lj + 8*q;
          bool ok = (s < 21) && !(s == 19 && !vp) && !(s == 20 && !vn);
          if (ok) m = fmaxf(m, e_s[dst*22 + s]);
        }
        m = fmaxf(m, __shfl_xor(m, 1));
        m = fmaxf(m, __shfl_xor(m, 2));
        m = fmaxf(m, __shfl_xor(m, 4));
        float sum = 0.f;
        #pragma unroll
        for (int q = 0; q < 3; ++q){
          int s = lj + 8*q;
          bool ok = (s < 21) && !(s == 19 && !vp) && !(s == 20 && !vn);
          if (ok){
            float ex = __expf(e_s[dst*22 + s] - m);
            e_s[dst*22 + s] = ex;
            sum += ex;
          }
        }
        sum += __shfl_xor(sum, 1);
        sum += __shfl_xor(sum, 2);
        sum += __shfl_xor(sum, 4);
        if (lj == 0) e_s[dst*22 + 21] = 1.f / (sum + 1e-16f);
      }
      __syncthreads();

      // agg -> scale -> +bias -> elu -> score/q partials
      if (t < 190){
        int dst = t / 10, c0 = (t % 10) * 8;
        float acc[8];
        #pragma unroll
        for (int jj = 0; jj < 8; ++jj) acc[jj] = 0.f;
        for (int s = 0; s < 21; ++s){
          if ((s == 19 && !vp) || (s == 20 && !vn)) continue;
          int row = (s < 19) ? s : (s == 19 ? 19 + dst : 38 + dst);
          float al = e_s[dst*22 + s];
          f16x8 v = *(const f16x8*)&xl_s[row*88 + c0];
          #pragma unroll
          for (int jj = 0; jj < 8; ++jj) acc[jj] = fmaf(al, (float)v[jj], acc[jj]);
        }
        float inv = e_s[dst*22 + 21];
        float sp = 0.f, fq = 0.f;
        #pragma unroll
        for (int k = 0; k < 8; ++k){
          float v = fmaf(inv, acc[k], cb_s[c0 + k]);
          v = (v > 0.f) ? v : (__expf(v) - 1.f);   // elu via fast exp
          sp += v * wp_s[c0 + k];
          fq += v * wf_s[c0 + k];
        }
        atomicAdd(&score_s[dst], sp);
        atomicAdd(&q_s[dst], fq);
      }
      __syncthreads();
      if (t < 19){
        size_t o = ((size_t)h*B + b)*NN + (size_t)w*NE + t;
        scp[o] = score_s[t];
        qp[o]  = q_s[t];
      }
    }
  }
  grid_barrier(ctr + 2, ctr + 3, 3);

  // ===== phase D: finale (k3), blocks 0..15 =====
  if (bid < B){
    int b = bid;
    float* ss  = (float*)smem;          /* 570 */
    float* qq  = ss + 570;              /* 570 */
    float* red = qq + 570;              /* 4 */
    float* rs  = red + 4;
    float* rq  = rs + 4;
    float bp = bpool[0];
    for (int i = t; i < NN; i += 256){
      float v = bp, q = 0.f;
      #pragma unroll
      for (int h = 0; h < NH; ++h){
        v += scp[((size_t)h*B + b)*NN + i];
        q += qp [((size_t)h*B + b)*NN + i];
      }
      ss[i] = v; qq[i] = q;
    }
    __syncthreads();
    float m = -1e30f;
    for (int i = t; i < NN; i += 256) m = fmaxf(m, ss[i]);
    for (int off = 32; off > 0; off >>= 1) m = fmaxf(m, __shfl_down(m, off));
    int wid = t >> 6, lane = t & 63;
    if (lane == 0) red[wid] = m;
    __syncthreads();
    if (t == 0) red[0] = fmaxf(fmaxf(red[0], red[1]), fmaxf(red[2], red[3]));
    __syncthreads();
    m = red[0];
    float s = 0.f, qs = 0.f;
    for (int i = t; i < NN; i += 256){
      float e = __expf(ss[i] - m);
      s += e; qs += e * qq[i];
    }
    for (int off = 32; off > 0; off >>= 1){
      s  += __shfl_down(s, off);
      qs += __shfl_down(qs, off);
    }
    if (lane == 0){ rs[wid] = s; rq[wid] = qs; }
    __syncthreads();
    if (t == 0){
      float S = rs[0] + rs[1] + rs[2] + rs[3];
      float Q = rq[0] + rq[1] + rq[2] + rq[3];
      out[b] = Q / (S + 1e-16f) + bfc[0];
    }
  }
}

// ---------------------------------------------------------------------------
extern "C" void kernel_launch(void* const* d_in, const int* in_sizes, int n_in,
                              void* d_out, int out_size, void* d_ws, size_t ws_size,
                              hipStream_t stream){
  const float* x     = (const float*)d_in[0];
  /* d_in[1] = edge_index — static topology, hardcoded */
  const float* Wl    = (const float*)d_in[2];
  const float* bl    = (const float*)d_in[3];
  const float* Wr    = (const float*)d_in[4];
  const float* br    = (const float*)d_in[5];
  const float* att   = (const float*)d_in[6];
  const float* cb    = (const float*)d_in[7];
  const float* wpool = (const float*)d_in[8];
  const float* bpool = (const float*)d_in[9];
  const float* wfc   = (const float*)d_in[10];
  const float* bfc   = (const float*)d_in[11];

  float* ws      = (float*)d_ws;
  _Float16* wph  = (_Float16*)(ws + WT_OFF);
  _Float16* wpl  = wph + 1280*NF;
  _Float16* xlb  = (_Float16*)(ws + XL_OFF);
  _Float16* xrb  = (_Float16*)(ws + XR_OFF);
  _Float16* xph  = (_Float16*)(ws + XT_OFF);
  _Float16* xpl  = xph + (size_t)NROW*NF;
  float* scp     = ws + SCP_OFF;
  float* qp      = ws + QP_OFF;
  unsigned* ctr  = (unsigned*)(ws + CTR_OFF);

  kinit<<<1, 64, 0, stream>>>(ctr);
  mega <<<NBLK, 256, 0, stream>>>(Wl, Wr, x, bl, br, att, cb, wpool, bpool,
                                  wfc, bfc, wph, wpl, xph, xpl, xlb, xrb,
                                  scp, qp, (float*)d_out, ctr);
}